// Round 1
// baseline (854.358 us; speedup 1.0000x reference)
//
#include <hip/hip_runtime.h>

#define NN 50000
#define NE 800000
#define NG 64
#define FD 128

// ---------- CSR build ----------

__global__ void k_count(const int* __restrict__ dst, int* __restrict__ indeg) {
  int e = blockIdx.x * 256 + threadIdx.x;
  if (e < NE) atomicAdd(&indeg[dst[e]], 1);
}

__global__ void k_scan(const int* __restrict__ indeg, int* __restrict__ row_off) {
  __shared__ int sums[257];
  int t = threadIdx.x;
  const int CHUNK = (NN + 255) / 256;  // 196
  int base = t * CHUNK;
  int s = 0;
  for (int i = 0; i < CHUNK; ++i) {
    int idx = base + i;
    if (idx < NN) s += indeg[idx];
  }
  sums[t] = s;
  __syncthreads();
  if (t == 0) {
    int run = 0;
    for (int i = 0; i < 256; ++i) { int v = sums[i]; sums[i] = run; run += v; }
    sums[256] = run;
  }
  __syncthreads();
  int run = sums[t];
  for (int i = 0; i < CHUNK; ++i) {
    int idx = base + i;
    if (idx < NN) { row_off[idx] = run; run += indeg[idx]; }
  }
  if (t == 0) row_off[NN] = sums[256];
}

__global__ void k_dinv_cursor(const int* __restrict__ indeg, const int* __restrict__ row_off,
                              float* __restrict__ dinv, int* __restrict__ cursor) {
  int i = blockIdx.x * 256 + threadIdx.x;
  if (i < NN) {
    dinv[i] = rsqrtf((float)(indeg[i] + 1));  // +1 self-loop; deg >= 1 always
    cursor[i] = row_off[i];
  }
}

__global__ void k_fill(const int* __restrict__ src, const int* __restrict__ dst,
                       int* __restrict__ cursor, int* __restrict__ csr_src) {
  int e = blockIdx.x * 256 + threadIdx.x;
  if (e < NE) {
    int pos = atomicAdd(&cursor[dst[e]], 1);
    csr_src[pos] = src[e];
  }
}

// ---------- dense: g[i][:] = dinv[i] * (h[i][:] @ W) ----------
// block = 256 threads: 8 row-tiles x 32 col-tiles; each thread 4 rows x 4 cols.

__global__ void k_matmul(const float* __restrict__ h, const float* __restrict__ W,
                         const float* __restrict__ dinv, float* __restrict__ g) {
  int tid = threadIdx.x;
  int rt = tid >> 5, ct = tid & 31;
  int r0 = blockIdx.x * 32 + rt * 4;
  int j0 = ct * 4;
  const float4* hp[4];
#pragma unroll
  for (int rr = 0; rr < 4; ++rr) {
    int r = r0 + rr;
    if (r > NN - 1) r = NN - 1;  // clamp to stay in-bounds; result discarded
    hp[rr] = (const float4*)(h + (size_t)r * FD);
  }
  float acc[4][4] = {};
  for (int k4 = 0; k4 < FD / 4; ++k4) {
    float wv[4][4];
#pragma unroll
    for (int kk = 0; kk < 4; ++kk) {
      float4 t = *(const float4*)(W + (k4 * 4 + kk) * FD + j0);
      wv[kk][0] = t.x; wv[kk][1] = t.y; wv[kk][2] = t.z; wv[kk][3] = t.w;
    }
#pragma unroll
    for (int rr = 0; rr < 4; ++rr) {
      float4 hv = hp[rr][k4];
      float hvv[4] = {hv.x, hv.y, hv.z, hv.w};
#pragma unroll
      for (int kk = 0; kk < 4; ++kk)
#pragma unroll
        for (int jj = 0; jj < 4; ++jj)
          acc[rr][jj] = fmaf(hvv[kk], wv[kk][jj], acc[rr][jj]);
    }
  }
#pragma unroll
  for (int rr = 0; rr < 4; ++rr) {
    int r = r0 + rr;
    if (r < NN) {
      float d = dinv[r];
      float4 o;
      o.x = acc[rr][0] * d; o.y = acc[rr][1] * d;
      o.z = acc[rr][2] * d; o.w = acc[rr][3] * d;
      *(float4*)(g + (size_t)r * FD + j0) = o;
    }
  }
}

// ---------- sparse: out[i] = relu(dinv[i] * (sum_{src in N(i)} g[src] + g[i]) + b) ----------
// 2 nodes per 256-thread block; 128 lanes = feature dim (coalesced 512B per edge gather).

__global__ void k_agg(const float* __restrict__ g, const int* __restrict__ row_off,
                      const int* __restrict__ csr_src, const float* __restrict__ dinv,
                      const float* __restrict__ bias, float* __restrict__ out) {
  int node = blockIdx.x * 2 + (threadIdx.x >> 7);
  int f = threadIdx.x & 127;
  if (node >= NN) return;
  float acc = g[(size_t)node * FD + f];  // self-loop term
  int e0 = row_off[node], e1 = row_off[node + 1];
  for (int e = e0; e < e1; ++e) {
    int s = csr_src[e];
    acc += g[(size_t)s * FD + f];
  }
  float v = dinv[node] * acc + bias[f];
  out[(size_t)node * FD + f] = v > 0.f ? v : 0.f;
}

// ---------- pooling: batch is sorted -> run-length local accumulate, flush on change ----------

__global__ void k_pool(const float* __restrict__ h, const int* __restrict__ batch,
                       float* __restrict__ addp, float* __restrict__ cnt,
                       unsigned int* __restrict__ maxp) {
  const int PN = 64;
  int f = threadIdx.x;  // 0..127
  int n0 = blockIdx.x * PN;
  if (n0 >= NN) return;
  int n1 = n0 + PN; if (n1 > NN) n1 = NN;
  int curg = batch[n0];
  float s = 0.f, m = 0.f;
  int c = 0;
  for (int n = n0; n < n1; ++n) {
    int gi = batch[n];
    if (gi != curg) {
      atomicAdd(&addp[curg * FD + f], s);
      atomicMax(&maxp[curg * FD + f], __float_as_uint(m));
      if (f == 0) atomicAdd(&cnt[curg], (float)c);
      s = 0.f; m = 0.f; c = 0; curg = gi;
    }
    float v = h[(size_t)n * FD + f];
    s += v;
    m = fmaxf(m, v);
    c += 1;
  }
  atomicAdd(&addp[curg * FD + f], s);
  atomicMax(&maxp[curg * FD + f], __float_as_uint(m));  // h >= 0 (post-relu), so uint order == float order
  if (f == 0) atomicAdd(&cnt[curg], (float)c);
}

// ---------- enc assembly + 2-layer MLP (tiny) ----------

__global__ void k_final(const float* __restrict__ addp, const float* __restrict__ cnt,
                        const unsigned int* __restrict__ maxp,
                        const float* __restrict__ l1w, const float* __restrict__ l1b,
                        const float* __restrict__ l2w, const float* __restrict__ l2b,
                        float* __restrict__ d_out) {
  __shared__ float enc_s[384];
  __shared__ float hid_s[128];
  int gph = blockIdx.x, j = threadIdx.x;
  float a = addp[gph * FD + j];
  float c = cnt[gph];
  float mn = a / fmaxf(c, 1.f);
  float mx = __uint_as_float(maxp[gph * FD + j]);
  enc_s[j] = a; enc_s[128 + j] = mn; enc_s[256 + j] = mx;
  float* enc_out = d_out + 2 * NG;  // enc follows out in flat d_out
  enc_out[gph * 384 + j] = a;
  enc_out[gph * 384 + 128 + j] = mn;
  enc_out[gph * 384 + 256 + j] = mx;
  __syncthreads();
  float sacc = l1b[j];
  for (int k = 0; k < 384; ++k) sacc = fmaf(enc_s[k], l1w[k * FD + j], sacc);
  hid_s[j] = fmaxf(sacc, 0.f);
  __syncthreads();
  if (j < 2) {
    float o = l2b[j];
    for (int k = 0; k < FD; ++k) o = fmaf(hid_s[k], l2w[k * 2 + j], o);
    d_out[gph * 2 + j] = o;
  }
}

extern "C" void kernel_launch(void* const* d_in, const int* in_sizes, int n_in,
                              void* d_out, int out_size, void* d_ws, size_t ws_size,
                              hipStream_t stream) {
  const float* x      = (const float*)d_in[0];
  const int*   edge   = (const int*)d_in[1];
  const int*   batch  = (const int*)d_in[2];
  const float* conv_w = (const float*)d_in[3];
  const float* conv_b = (const float*)d_in[4];
  const float* l1w    = (const float*)d_in[5];
  const float* l1b    = (const float*)d_in[6];
  const float* l2w    = (const float*)d_in[7];
  const float* l2b    = (const float*)d_in[8];
  float* out = (float*)d_out;

  const int* esrc = edge;        // edge_index[0]
  const int* edst = edge + NE;   // edge_index[1]

  char* wsp = (char*)d_ws;
  auto alloc = [&](size_t bytes) -> char* {
    char* p = wsp;
    wsp += (bytes + 255) & ~(size_t)255;
    return p;
  };
  float* bufA    = (float*)alloc(sizeof(float) * NN * FD);    // 25.6 MB
  float* bufB    = (float*)alloc(sizeof(float) * NN * FD);    // 25.6 MB
  int*   csr_src = (int*)alloc(sizeof(int) * NE);             // 3.2 MB
  int*   indeg   = (int*)alloc(sizeof(int) * NN);
  int*   row_off = (int*)alloc(sizeof(int) * (NN + 1));
  int*   cursor  = (int*)alloc(sizeof(int) * NN);
  float* dinv    = (float*)alloc(sizeof(float) * NN);
  float* addp    = (float*)alloc(sizeof(float) * NG * FD);
  float* cnt     = (float*)alloc(sizeof(float) * NG);
  unsigned int* maxp = (unsigned int*)alloc(sizeof(unsigned int) * NG * FD);

  hipMemsetAsync(indeg, 0, sizeof(int) * NN, stream);
  hipMemsetAsync(addp, 0, sizeof(float) * NG * FD, stream);
  hipMemsetAsync(cnt, 0, sizeof(float) * NG, stream);
  hipMemsetAsync(maxp, 0, sizeof(unsigned int) * NG * FD, stream);

  k_count<<<(NE + 255) / 256, 256, 0, stream>>>(edst, indeg);
  k_scan<<<1, 256, 0, stream>>>(indeg, row_off);
  k_dinv_cursor<<<(NN + 255) / 256, 256, 0, stream>>>(indeg, row_off, dinv, cursor);
  k_fill<<<(NE + 255) / 256, 256, 0, stream>>>(esrc, edst, cursor, csr_src);

  const float* hin = x;
  for (int l = 0; l < 3; ++l) {
    k_matmul<<<(NN + 31) / 32, 256, 0, stream>>>(hin, conv_w + l * FD * FD, dinv, bufA);
    k_agg<<<(NN + 1) / 2, 256, 0, stream>>>(bufA, row_off, csr_src, dinv, conv_b + l * FD, bufB);
    hin = bufB;
  }

  k_pool<<<(NN + 63) / 64, 128, 0, stream>>>(bufB, batch, addp, cnt, maxp);
  k_final<<<NG, 128, 0, stream>>>(addp, cnt, maxp, l1w, l1b, l2w, l2b, out);
}